// Round 2
// baseline (11622.407 us; speedup 1.0000x reference)
//
#include <hip/hip_runtime.h>

#define HW 262144   // 512*512
#define EPSF 1e-5f

// ---------------------------------------------------------------------------
// K1: dense 1x1 conv  y[n][co][p] = sum_ci wd[co][ci] * x[n][ci][p] + bd[co]
// One thread per pixel; x channels in registers; wd reads are wave-uniform
// (scalar loads). Writes ALL of y (block regions get overwritten by K2).
// ---------------------------------------------------------------------------
__global__ __launch_bounds__(256) void k1_dense(const float* __restrict__ x,
                                                const float* __restrict__ wd,
                                                const float* __restrict__ bd,
                                                float* __restrict__ y) {
    const int p   = blockIdx.x * 256 + threadIdx.x;   // 0 .. N*HW-1
    const int n   = p >> 18;                          // / HW
    const int pix = p & (HW - 1);
    const float* xb = x + (size_t)n * 64 * HW + pix;
    float xv[64];
    #pragma unroll
    for (int ci = 0; ci < 64; ++ci) xv[ci] = xb[(size_t)ci * HW];
    float* yb = y + (size_t)n * 256 * HW + pix;
    #pragma unroll 1
    for (int co = 0; co < 256; ++co) {
        const float* w = wd + co * 64;                // uniform -> s_loads
        float acc = bd[co];
        #pragma unroll
        for (int ci = 0; ci < 64; ++ci) acc = fmaf(w[ci], xv[ci], acc);
        yb[(size_t)co * HW] = acc;
    }
}

// ---------------------------------------------------------------------------
// K2: fused sparse pipeline.  WG = (block, co-tile of 64, row-tile of 8).
// Loops over 16 tiles of 16 h-channels:
//   stage BN1-folded w1 tile + w2 tile in LDS, compute h tile (with halo,
//   zero-padded at block borders) in LDS, then conv2-accumulate into 64
//   fp32 registers per thread.  Epilogue: BN2 + relu + scatter into y.
// ---------------------------------------------------------------------------
__global__ __launch_bounds__(256) void k2_sparse(
    const float* __restrict__ x, const int* __restrict__ indices,
    const float* __restrict__ w1, const float* __restrict__ b1,
    const float* __restrict__ g1, const float* __restrict__ be1,
    const float* __restrict__ m1, const float* __restrict__ v1,
    const float* __restrict__ w2, const float* __restrict__ b2,
    const float* __restrict__ g2, const float* __restrict__ be2,
    const float* __restrict__ m2, const float* __restrict__ v2,
    const int* __restrict__ bstride, const int* __restrict__ boff,
    float* __restrict__ y)
{
    __shared__ float hS[16][10][34];               // 21760 B  h tile (halo+pad)
    __shared__ __align__(16) float w2S[144 * 68];  // 39168 B  [tc*9+tap][co], pad 68 for b128 align
    __shared__ float w1S[16 * 64];                 //  4096 B  BN-scaled w1 tile
    // total 65024 B (<= 64 KiB static limit) -> 2 WG/CU

    const int t   = threadIdx.x;
    const int blk = blockIdx.x;
    const int cz  = blockIdx.y;        // 0..3  co tile
    const int rz  = blockIdx.z;        // 0..3  row tile
    const int bn  = indices[blk*3+0];
    const int gr  = indices[blk*3+1];
    const int gc  = indices[blk*3+2];
    const int stride = bstride[0], off = boff[0];
    const int row0 = gr*stride + off;
    const int col0 = gc*stride + off;
    const int cobase = cz*64;

    // zero h column borders once (cols 0 and 33 are permanent zero-pad)
    for (int i = t; i < 160; i += 256) {
        int tc = i / 10, hr = i % 10;
        hS[tc][hr][0]  = 0.f;
        hS[tc][hr][33] = 0.f;
    }

    float acc[64];
    #pragma unroll
    for (int i = 0; i < 64; ++i) acc[i] = 0.f;

    const int rl = t >> 5;     // output row in tile (0..7)
    const int cl = t & 31;     // output col (0..31)

    for (int kc = 0; kc < 16; ++kc) {
        __syncthreads();   // guards hS/w2S/w1S rewrite vs previous readers

        // ---- stage w1 tile, folded with BN1 scale ----
        #pragma unroll
        for (int k = 0; k < 4; ++k) {
            int i = t + k*256;                 // 0..1023
            int q = i >> 6;                    // h channel within tile
            int hcg = kc*16 + q;
            float s1 = g1[hcg] * rsqrtf(v1[hcg] + EPSF);
            w1S[i] = w1[kc*1024 + i] * s1;
        }
        // ---- stage w2 tile: w2S[tc*9+tap][co] ----
        for (int e = t; e < 9216; e += 256) {
            int co = e / 144, rt = e % 144;
            int tc = rt / 9,  tap = rt % 9;
            w2S[rt*68 + co] =
                w2[(size_t)(cobase+co)*2304 + (size_t)(kc*16+tc)*9 + tap];
        }
        // ---- compute h tile: rows rz*8-1 .. rz*8+8 (halo), 32 cols ----
        for (int p = t; p < 320; p += 256) {
            int hr = p >> 5, hc = p & 31;
            int br = rz*8 + hr - 1;            // block-local row
            bool valid = ((unsigned)br < 32u);
            float a[16];
            #pragma unroll
            for (int q = 0; q < 16; ++q) a[q] = 0.f;
            if (valid) {
                const float* xp = x + (size_t)bn*64*HW
                                    + (size_t)(row0 + br)*512 + (col0 + hc);
                #pragma unroll 4
                for (int ci = 0; ci < 64; ++ci) {
                    float xv = xp[(size_t)ci * HW];
                    #pragma unroll
                    for (int q = 0; q < 16; ++q)
                        a[q] = fmaf(w1S[q*64 + ci], xv, a[q]);
                }
            }
            #pragma unroll
            for (int q = 0; q < 16; ++q) {
                int hcg = kc*16 + q;
                float s1 = g1[hcg] * rsqrtf(v1[hcg] + EPSF);
                float t1 = fmaf(b1[hcg] - m1[hcg], s1, be1[hcg]);
                hS[q][hr][1+hc] = valid ? fmaxf(a[q] + t1, 0.f) : 0.f;
            }
        }
        __syncthreads();

        // ---- conv2 accumulate: 64 FMAs per broadcast w2 float4 ----
        #pragma unroll 1
        for (int tc = 0; tc < 16; ++tc) {
            #pragma unroll
            for (int dy = 0; dy < 3; ++dy) {
                #pragma unroll
                for (int dx = 0; dx < 3; ++dx) {
                    float hv = hS[tc][rl+dy][cl+dx];
                    const float4* wrow =
                        (const float4*)&w2S[(tc*9 + dy*3 + dx)*68];
                    #pragma unroll
                    for (int cg = 0; cg < 16; ++cg) {
                        float4 w4 = wrow[cg];
                        acc[cg*4+0] = fmaf(w4.x, hv, acc[cg*4+0]);
                        acc[cg*4+1] = fmaf(w4.y, hv, acc[cg*4+1]);
                        acc[cg*4+2] = fmaf(w4.z, hv, acc[cg*4+2]);
                        acc[cg*4+3] = fmaf(w4.w, hv, acc[cg*4+3]);
                    }
                }
            }
        }
    }

    // ---- epilogue: BN2 + relu + scatter (fully unrolled: static acc idx) ----
    float* yp = y + ((size_t)bn*256 + cobase)*HW
                  + (size_t)(row0 + rz*8 + rl)*512 + (col0 + cl);
    #pragma unroll
    for (int co = 0; co < 64; ++co) {
        int cog = cobase + co;
        float s2 = g2[cog] * rsqrtf(v2[cog] + EPSF);
        float t2 = fmaf(b2[cog] - m2[cog], s2, be2[cog]);
        yp[(size_t)co * HW] = fmaxf(fmaf(acc[co], s2, t2), 0.f);
    }
}

// ---------------------------------------------------------------------------
extern "C" void kernel_launch(void* const* d_in, const int* in_sizes, int n_in,
                              void* d_out, int out_size, void* d_ws, size_t ws_size,
                              hipStream_t stream) {
    const float* x       = (const float*)d_in[0];
    // d_in[1] = mask (unused)
    const int*   indices = (const int*)  d_in[2];
    const float* w1  = (const float*)d_in[3];
    const float* b1  = (const float*)d_in[4];
    const float* g1  = (const float*)d_in[5];
    const float* be1 = (const float*)d_in[6];
    const float* m1  = (const float*)d_in[7];
    const float* v1  = (const float*)d_in[8];
    const float* w2  = (const float*)d_in[9];
    const float* b2  = (const float*)d_in[10];
    const float* g2  = (const float*)d_in[11];
    const float* be2 = (const float*)d_in[12];
    const float* m2  = (const float*)d_in[13];
    const float* v2  = (const float*)d_in[14];
    // d_in[15..20] = w3/b3/g3/be3/m3/v3 (unused by the reference output)
    const float* wd  = (const float*)d_in[21];
    const float* bd  = (const float*)d_in[22];
    // d_in[23] = block_size (structure assumes 32)
    const int* bstride = (const int*)d_in[24];
    const int* boff    = (const int*)d_in[25];
    float* y = (float*)d_out;

    const int nB = in_sizes[2] / 3;   // number of sparse blocks (256)

    // dense base: 2*512*512 pixels / 256 threads
    hipLaunchKernelGGL(k1_dense, dim3(2 * HW / 256), dim3(256), 0, stream,
                       x, wd, bd, y);
    // fused sparse pipeline
    hipLaunchKernelGGL(k2_sparse, dim3(nB, 4, 4), dim3(256), 0, stream,
                       x, indices, w1, b1, g1, be1, m1, v1,
                       w2, b2, g2, be2, m2, v2, bstride, boff, y);
}

// Round 3
// 5415.295 us; speedup vs baseline: 2.1462x; 2.1462x over previous
//
#include <hip/hip_runtime.h>

#define HW 262144   // 512*512
#define EPSF 1e-5f

typedef __attribute__((ext_vector_type(8))) short bf16x8;
typedef __attribute__((ext_vector_type(4))) float f32x4;

__device__ __forceinline__ unsigned short f2bf(float f) {
    unsigned u = __builtin_bit_cast(unsigned, f);
    return (unsigned short)((u + 0x7FFFu + ((u >> 16) & 1u)) >> 16);  // RNE
}

// ---------------------------------------------------------------------------
// K1: dense 1x1 conv (unchanged from round 2; ~140us, store-bound)
// ---------------------------------------------------------------------------
__global__ __launch_bounds__(256) void k1_dense(const float* __restrict__ x,
                                                const float* __restrict__ wd,
                                                const float* __restrict__ bd,
                                                float* __restrict__ y) {
    const int p   = blockIdx.x * 256 + threadIdx.x;
    const int n   = p >> 18;
    const int pix = p & (HW - 1);
    const float* xb = x + (size_t)n * 64 * HW + pix;
    float xv[64];
    #pragma unroll
    for (int ci = 0; ci < 64; ++ci) xv[ci] = xb[(size_t)ci * HW];
    float* yb = y + (size_t)n * 256 * HW + pix;
    #pragma unroll 1
    for (int co = 0; co < 256; ++co) {
        const float* w = wd + co * 64;          // uniform -> s_loads
        float acc = bd[co];
        #pragma unroll
        for (int ci = 0; ci < 64; ++ci) acc = fmaf(w[ci], xv[ci], acc);
        yb[(size_t)co * HW] = acc;
    }
}

// ---------------------------------------------------------------------------
// K2: fused sparse pipeline, conv2 via MFMA 16x16x32 bf16.
// WG = (block, co-tile 64, row-tile 8). 256 thr = 4 waves.
// Per hc-chunk of 32: stage w2 (bf16, LDS) + compute h (VALU, bf16 LDS,
// hc-innermost) ; then conv2 = 9 taps x MFMA with shifted-h B-fragments.
// Wave wv: rows [wv*2, wv*2+2), all 32 cols, all 64 co of the WG tile.
//   acc[p][a2]: p = pxtile (row p>>1 of 2, colhalf p&1), a2 = co subtile.
// ---------------------------------------------------------------------------
__global__ __launch_bounds__(256, 2) void k2_sparse(
    const float* __restrict__ x, const int* __restrict__ indices,
    const float* __restrict__ w1, const float* __restrict__ b1,
    const float* __restrict__ g1, const float* __restrict__ be1,
    const float* __restrict__ m1, const float* __restrict__ v1,
    const float* __restrict__ w2, const float* __restrict__ b2,
    const float* __restrict__ g2, const float* __restrict__ be2,
    const float* __restrict__ m2, const float* __restrict__ v2,
    const int* __restrict__ bstride, const int* __restrict__ boff,
    float* __restrict__ y)
{
    // w2S[co][tap][hc]: stride 296 ushort (=148 words, 20 mod 32 -> 2-way max)
    __shared__ __align__(16) unsigned short w2S[64 * 296];     // 37,888 B
    // hS[row 0..9][col 0..33][hc 0..31 pad 40]: col stride 80B (16B-aligned,
    // 20 words mod 32 -> 2-way max). row 0 = block row (pz*8 - 1).
    __shared__ __align__(16) unsigned short hS[10 * 34 * 40];  // 27,200 B
    // total 65,088 B  -> 2 WG/CU

    const int t    = threadIdx.x;
    const int lane = t & 63;
    const int wv   = t >> 6;         // wave 0..3 -> rows wv*2..wv*2+1
    const int m    = lane & 15;      // MFMA 16-index
    const int g    = lane >> 4;      // MFMA k-group / D row group

    const int blk = blockIdx.x;
    const int cz  = blockIdx.y & 3;  // co tile of 64
    const int pz  = blockIdx.y >> 2; // row tile of 8
    const int bn = indices[blk*3+0], gr = indices[blk*3+1], gc = indices[blk*3+2];
    const int stride = bstride[0], off = boff[0];
    const int row0 = gr*stride + off, col0 = gc*stride + off;
    const int cobase = cz*64;

    f32x4 acc[4][4];
    #pragma unroll
    for (int p = 0; p < 4; ++p)
        #pragma unroll
        for (int a2 = 0; a2 < 4; ++a2) acc[p][a2] = (f32x4){0.f,0.f,0.f,0.f};

    for (int ch = 0; ch < 8; ++ch) {
        const int hc0 = ch * 32;
        __syncthreads();   // prev-chunk conv2 done before rewriting LDS

        // ---- stage w2 chunk: [64 co][9 tap][32 hc] bf16, paired u32 writes
        #pragma unroll 1
        for (int i = 0; i < 36; ++i) {
            int e = t + i*256;                  // 0..9215
            int co = e / 144, rem = e % 144;
            int tap = rem >> 4, hc2 = rem & 15;
            const float* wp = w2 + (size_t)(cobase+co)*2304
                                 + (size_t)(hc0 + 2*hc2)*9 + tap;
            unsigned pv = (unsigned)f2bf(wp[0]) | ((unsigned)f2bf(wp[9]) << 16);
            ((unsigned*)w2S)[co*148 + tap*16 + hc2] = pv;
        }

        // ---- compute h chunk: 10x34 positions, 32 hc each (VALU, fp32) ----
        #pragma unroll 1
        for (int pos = t; pos < 340; pos += 256) {
            int row = pos / 34, col = pos % 34;
            int br = pz*8 + row - 1, bc = col - 1;       // block-local
            bool valid = ((unsigned)br < 32u) && ((unsigned)bc < 32u);
            float a32[32];
            #pragma unroll
            for (int q = 0; q < 32; ++q) a32[q] = 0.f;
            if (valid) {
                const float* xp = x + (size_t)bn*64*HW
                                    + (size_t)(row0+br)*512 + (col0+bc);
                const float* wr = w1 + hc0*64;           // uniform -> s_loads
                #pragma unroll 4
                for (int ci = 0; ci < 64; ++ci) {
                    float xv = xp[(size_t)ci * HW];
                    #pragma unroll
                    for (int q = 0; q < 32; ++q)
                        a32[q] = fmaf(wr[q*64 + ci], xv, a32[q]);
                }
            }
            unsigned* hp = ((unsigned*)hS) + (row*34 + col)*20;
            #pragma unroll
            for (int q2 = 0; q2 < 16; ++q2) {
                int h0 = hc0 + 2*q2, h1 = h0 + 1;
                float s1a = g1[h0] * rsqrtf(v1[h0] + EPSF);
                float s1b = g1[h1] * rsqrtf(v1[h1] + EPSF);
                float t1a = fmaf(b1[h0] - m1[h0], s1a, be1[h0]);
                float t1b = fmaf(b1[h1] - m1[h1], s1b, be1[h1]);
                float va = valid ? fmaxf(fmaf(a32[2*q2],   s1a, t1a), 0.f) : 0.f;
                float vb = valid ? fmaxf(fmaf(a32[2*q2+1], s1b, t1b), 0.f) : 0.f;
                hp[q2] = (unsigned)f2bf(va) | ((unsigned)f2bf(vb) << 16);
            }
        }
        __syncthreads();

        // ---- conv2: 9 taps x (4 A-frags, 4 B-frags, 16 MFMA) ----
        #pragma unroll 1
        for (int tap = 0; tap < 9; ++tap) {
            const int dy = tap / 3, dx = tap % 3;
            bf16x8 aF[4];
            #pragma unroll
            for (int a2 = 0; a2 < 4; ++a2)
                aF[a2] = *(const bf16x8*)&w2S[(a2*16 + m)*296 + tap*32 + g*8];
            #pragma unroll
            for (int p = 0; p < 4; ++p) {
                int hrow = wv*2 + (p>>1) + dy;          // 0..9
                int hcol = (p&1)*16 + m + dx;           // 0..33
                bf16x8 bF = *(const bf16x8*)&hS[(hrow*34 + hcol)*40 + g*8];
                #pragma unroll
                for (int a2 = 0; a2 < 4; ++a2)
                    acc[p][a2] = __builtin_amdgcn_mfma_f32_16x16x32_bf16(
                                     aF[a2], bF, acc[p][a2], 0, 0, 0);
            }
        }
    }

    // ---- epilogue: BN2 + relu + scatter.  D: row=g*4+jj (co), col=m (px) ----
    #pragma unroll
    for (int a2 = 0; a2 < 4; ++a2) {
        #pragma unroll
        for (int jj = 0; jj < 4; ++jj) {
            int co = cobase + a2*16 + g*4 + jj;
            float s2 = g2[co] * rsqrtf(v2[co] + EPSF);
            float t2 = fmaf(b2[co] - m2[co], s2, be2[co]);
            float* yp = y + ((size_t)bn*256 + co)*HW;
            #pragma unroll
            for (int p = 0; p < 4; ++p) {
                int grow = row0 + pz*8 + wv*2 + (p>>1);
                int gcol = col0 + (p&1)*16 + m;
                yp[(size_t)grow*512 + gcol] =
                    fmaxf(fmaf(acc[p][a2][jj], s2, t2), 0.f);
            }
        }
    }
}

// ---------------------------------------------------------------------------
extern "C" void kernel_launch(void* const* d_in, const int* in_sizes, int n_in,
                              void* d_out, int out_size, void* d_ws, size_t ws_size,
                              hipStream_t stream) {
    const float* x       = (const float*)d_in[0];
    const int*   indices = (const int*)  d_in[2];
    const float* w1  = (const float*)d_in[3];
    const float* b1  = (const float*)d_in[4];
    const float* g1  = (const float*)d_in[5];
    const float* be1 = (const float*)d_in[6];
    const float* m1  = (const float*)d_in[7];
    const float* v1  = (const float*)d_in[8];
    const float* w2  = (const float*)d_in[9];
    const float* b2  = (const float*)d_in[10];
    const float* g2  = (const float*)d_in[11];
    const float* be2 = (const float*)d_in[12];
    const float* m2  = (const float*)d_in[13];
    const float* v2  = (const float*)d_in[14];
    const float* wd  = (const float*)d_in[21];
    const float* bd  = (const float*)d_in[22];
    const int* bstride = (const int*)d_in[24];
    const int* boff    = (const int*)d_in[25];
    float* y = (float*)d_out;

    const int nB = in_sizes[2] / 3;   // 256 blocks

    hipLaunchKernelGGL(k1_dense, dim3(2 * HW / 256), dim3(256), 0, stream,
                       x, wd, bd, y);
    // grid (block, 16 sub-WGs): x-dim fastest keeps a block's 16 sub-WGs on
    // one XCD (L2 locality for x re-reads and w2).
    hipLaunchKernelGGL(k2_sparse, dim3(nB, 16), dim3(256), 0, stream,
                       x, indices, w1, b1, g1, be1, m1, v1,
                       w2, b2, g2, be2, m2, v2, bstride, boff, y);
}

// Round 4
// 1097.583 us; speedup vs baseline: 10.5891x; 4.9338x over previous
//
#include <hip/hip_runtime.h>

#define HW 262144   // 512*512
#define EPSF 1e-5f

typedef __attribute__((ext_vector_type(8))) short bf16x8;
typedef __attribute__((ext_vector_type(4))) float f32x4;

__device__ __forceinline__ unsigned short f2bf(float f) {
    unsigned u = __builtin_bit_cast(unsigned, f);
    return (unsigned short)((u + 0x7FFFu + ((u >> 16) & 1u)) >> 16);  // RNE
}

typedef __attribute__((address_space(3))) unsigned lds_u32_t;
typedef __attribute__((address_space(1))) const unsigned glb_u32_t;
__device__ __forceinline__ void dma16(const void* gsrc, void* ldst) {
    __builtin_amdgcn_global_load_lds((glb_u32_t*)gsrc, (lds_u32_t*)ldst, 16, 0, 0);
}

// ws layout (bytes):
//   w2ws  @ 0        : [8ch][4cz][64co][296] ushort  = 1,212,416
//   w1ws  @ 1212416  : [256hc][72ci] ushort (BN1-folded) = 36,864
//   t1ws  @ 1249280  : float[256]
//   s2ws  @ 1250304  : float[256]
//   t2ws  @ 1251328  : float[256]   (total 1,252,352 B)
#define W2WS_OFF 0
#define W1WS_OFF 1212416
#define T1WS_OFF 1249280
#define S2WS_OFF 1250304
#define T2WS_OFF 1251328

// ---------------------------------------------------------------------------
// kprep: one-shot weight transform into MFMA/DMA-friendly workspace.
// ---------------------------------------------------------------------------
__global__ __launch_bounds__(256) void kprep(
    const float* __restrict__ w1, const float* __restrict__ b1,
    const float* __restrict__ g1, const float* __restrict__ be1,
    const float* __restrict__ m1, const float* __restrict__ v1,
    const float* __restrict__ w2, const float* __restrict__ b2,
    const float* __restrict__ g2, const float* __restrict__ be2,
    const float* __restrict__ m2, const float* __restrict__ v2,
    char* __restrict__ ws)
{
    unsigned short* w2ws = (unsigned short*)(ws + W2WS_OFF);
    unsigned short* w1ws = (unsigned short*)(ws + W1WS_OFF);
    float* t1ws = (float*)(ws + T1WS_OFF);
    float* s2ws = (float*)(ws + S2WS_OFF);
    float* t2ws = (float*)(ws + T2WS_OFF);

    const int bid = blockIdx.x, t = threadIdx.x;
    if (bid < 2304) {                      // w2: 589,824 elements
        int e  = bid*256 + t;
        int hc = e & 31;
        int r1 = e >> 5;
        int tap = r1 % 9;
        int r2 = r1 / 9;                   // < 2048
        int co = r2 & 63;
        int q  = r2 >> 6;                  // < 32
        int cz = q & 3, ch = q >> 2;
        float v = w2[(size_t)(cz*64+co)*2304 + (size_t)(ch*32+hc)*9 + tap];
        w2ws[((ch*4+cz)*64+co)*296 + tap*32 + hc] = f2bf(v);
    } else if (bid < 2368) {               // w1 folded: 16,384 elements
        int e = (bid-2304)*256 + t;
        int hc = e >> 6, ci = e & 63;
        float s1 = g1[hc] * rsqrtf(v1[hc] + EPSF);
        w1ws[hc*72 + ci] = f2bf(w1[hc*64+ci] * s1);
    } else {
        if (t < 256) {
            float s1 = g1[t] * rsqrtf(v1[t] + EPSF);
            t1ws[t] = (b1[t]-m1[t])*s1 + be1[t];
            float s2 = g2[t] * rsqrtf(v2[t] + EPSF);
            s2ws[t] = s2;
            t2ws[t] = (b2[t]-m2[t])*s2 + be2[t];
        }
    }
}

// ---------------------------------------------------------------------------
// K1: dense 1x1 conv (unchanged, known-good; ~550us, next round's target)
// ---------------------------------------------------------------------------
__global__ __launch_bounds__(256) void k1_dense(const float* __restrict__ x,
                                                const float* __restrict__ wd,
                                                const float* __restrict__ bd,
                                                float* __restrict__ y) {
    const int p   = blockIdx.x * 256 + threadIdx.x;
    const int n   = p >> 18;
    const int pix = p & (HW - 1);
    const float* xb = x + (size_t)n * 64 * HW + pix;
    float xv[64];
    #pragma unroll
    for (int ci = 0; ci < 64; ++ci) xv[ci] = xb[(size_t)ci * HW];
    float* yb = y + (size_t)n * 256 * HW + pix;
    #pragma unroll 1
    for (int co = 0; co < 256; ++co) {
        const float* w = wd + co * 64;
        float acc = bd[co];
        #pragma unroll
        for (int ci = 0; ci < 64; ++ci) acc = fmaf(w[ci], xv[ci], acc);
        yb[(size_t)co * HW] = acc;
    }
}

// ---------------------------------------------------------------------------
// k2_fused: WG = (block, pz row-stripe of 8). 512 thr = 8 waves.
// P0: stage xT [352px][72ci] bf16 (transposed, once).  Per chunk of 32 hc:
//   DMA w1 slice + w2(cz0) -> conv1 MFMA -> masked h [352px][32hc] ->
//   4x { conv2 MFMA (9 taps), DMA next cz }.  Epilogue: BN2+relu+scatter.
// All LDS layouts 16B-aligned rows, bank-balanced for b128 frags.
// ---------------------------------------------------------------------------
__global__ __launch_bounds__(512, 2) void k2_fused(
    const float* __restrict__ x, const int* __restrict__ indices,
    const char* __restrict__ ws,
    const int* __restrict__ bstride, const int* __restrict__ boff,
    float* __restrict__ y)
{
    extern __shared__ char smem[];
    unsigned short* xT  = (unsigned short*)smem;            // [352][72]  50,688B
    unsigned short* w1s = (unsigned short*)(smem + 50688);  // [32][72]    4,608B
    unsigned short* hS  = (unsigned short*)(smem + 55296);  // [352][32]  22,528B
    unsigned short* w2S = (unsigned short*)(smem + 77824);  // [64][296]  37,888B
    float* t1S = (float*)(smem + 115712);                   // 1KB
    float* s2S = (float*)(smem + 116736);                   // 1KB
    float* t2S = (float*)(smem + 117760);                   // 1KB  -> 118,784B

    const unsigned short* w2ws = (const unsigned short*)(ws + W2WS_OFF);
    const unsigned short* w1ws = (const unsigned short*)(ws + W1WS_OFF);

    const int t    = threadIdx.x;
    const int lane = t & 63;
    const int w    = t >> 6;          // wave 0..7 = output row within stripe
    const int m    = lane & 15;       // MFMA 16-index
    const int g    = lane >> 4;       // MFMA k-group / D row group

    const int bid = blockIdx.x;
    const int blk = bid >> 2, pz = bid & 3;
    const int bn = indices[blk*3+0], gr = indices[blk*3+1], gc = indices[blk*3+2];
    const int stride = bstride[0], off = boff[0];
    const int row0 = gr*stride + off, col0 = gc*stride + off;

    // ---- P0: DMA scalar tables (3KB, one wave each) ----
    if (t < 192) {
        const float* src = (t < 64) ? (const float*)(ws + T1WS_OFF)
                         : (t < 128) ? (const float*)(ws + S2WS_OFF)
                                     : (const float*)(ws + T2WS_OFF);
        float* dst = (t < 64) ? t1S : (t < 128) ? s2S : t2S;
        dma16(src + (lane)*4, dst + (lane)*4);
    }

    // ---- P0: stage xT (transpose to [px][ci], bf16). 640 (r,ci) pairs;
    // each wave-iter handles 2 pairs via 32-lane halves; coalesced loads.
    {
        const int half = lane >> 5, cc = lane & 31;
        for (int pb = w*80; pb < w*80 + 80; pb += 2) {
            int pi = pb + half;
            int r = pi >> 6, ci = pi & 63;
            int br = pz*8 + r - 1;
            if ((unsigned)br < 32u) {
                float xv = x[(size_t)bn*64*HW + (size_t)ci*HW
                             + (size_t)(row0+br)*512 + (col0+cc)];
                xT[(r*34 + cc + 1)*72 + ci] = f2bf(xv);
            }
            // invalid rows / cols 0,33 stay garbage: masked at h-write
        }
    }

    f32x4 acc[4][2][4];   // [cz][pxf][cof] - static indexing only
    #pragma unroll
    for (int a = 0; a < 4; ++a)
        #pragma unroll
        for (int b = 0; b < 2; ++b)
            #pragma unroll
            for (int c = 0; c < 4; ++c) acc[a][b][c] = (f32x4){0.f,0.f,0.f,0.f};

    #pragma unroll 1
    for (int ch = 0; ch < 8; ++ch) {
        __syncthreads();   // bar A: prev readers of w1s/w2S/hS done (and xT staged)

        // DMA w1 chunk slice (4,608B) + w2 (ch, cz=0) (37,888B)
        if (t < 288) dma16((const char*)w1ws + ch*4608 + t*16, (char*)w1s + t*16);
        {
            const char* ws2 = (const char*)w2ws + (size_t)(ch*4 + 0)*37888;
            #pragma unroll
            for (int i = 0; i < 4; ++i)
                dma16(ws2 + t*16 + i*8192, (char*)w2S + t*16 + i*8192);
            if (t < 320) dma16(ws2 + t*16 + 32768, (char*)w2S + t*16 + 32768);
        }
        __syncthreads();   // bar B: DMAs complete (syncthreads drains vmcnt)

        // ---- conv1 MFMA: wave w -> px-tiles w*3..w*3+2 (tile<22) ----
        f32x4 a1[3][2];
        #pragma unroll
        for (int i = 0; i < 3; ++i) { a1[i][0] = (f32x4){0,0,0,0}; a1[i][1] = (f32x4){0,0,0,0}; }
        #pragma unroll
        for (int i = 0; i < 3; ++i) {
            const int tile = w*3 + i;
            if (tile < 22) {
                #pragma unroll
                for (int kk = 0; kk < 2; ++kk) {
                    bf16x8 bF = *(const bf16x8*)&xT[(tile*16 + m)*72 + kk*32 + g*8];
                    #pragma unroll
                    for (int hct = 0; hct < 2; ++hct) {
                        bf16x8 aF = *(const bf16x8*)&w1s[(hct*16 + m)*72 + kk*32 + g*8];
                        a1[i][hct] = __builtin_amdgcn_mfma_f32_16x16x32_bf16(
                                         aF, bF, a1[i][hct], 0, 0, 0);
                    }
                }
            }
        }
        // ---- h write: BN1 bias + relu + border mask, bf16, b64 stores ----
        #pragma unroll
        for (int i = 0; i < 3; ++i) {
            const int tile = w*3 + i;
            if (tile < 22) {
                int p = tile*16 + m;
                int r = p / 34;
                int c = p - r*34;
                int br = pz*8 + r - 1;
                bool valid = (c >= 1) && (c <= 32) && ((unsigned)br < 32u);
                #pragma unroll
                for (int hct = 0; hct < 2; ++hct) {
                    unsigned short hv[4];
                    #pragma unroll
                    for (int j = 0; j < 4; ++j) {
                        float tv = t1S[ch*32 + hct*16 + g*4 + j];
                        float hf = fmaxf(a1[i][hct][j] + tv, 0.f);
                        hv[j] = valid ? f2bf(hf) : (unsigned short)0;
                    }
                    unsigned lo = (unsigned)hv[0] | ((unsigned)hv[1] << 16);
                    unsigned hi = (unsigned)hv[2] | ((unsigned)hv[3] << 16);
                    *(uint2*)&hS[p*32 + hct*16 + g*4] = make_uint2(lo, hi);
                }
            }
        }
        __syncthreads();   // bar C: h ready (w2S cz0 ready since bar B)

        // ---- conv2: 4 cz x 9 taps; wave w = output row w, 2 px-frags ----
        #pragma unroll
        for (int cz = 0; cz < 4; ++cz) {
            #pragma unroll
            for (int tap = 0; tap < 9; ++tap) {
                const int dy = tap/3, dx = tap%3;
                bf16x8 aF[4];
                #pragma unroll
                for (int cof = 0; cof < 4; ++cof)
                    aF[cof] = *(const bf16x8*)&w2S[(cof*16 + m)*296 + tap*32 + g*8];
                #pragma unroll
                for (int pxf = 0; pxf < 2; ++pxf) {
                    int p = (w + dy)*34 + pxf*16 + m + dx;
                    bf16x8 bF = *(const bf16x8*)&hS[p*32 + g*8];
                    if (cz == 0) {
                        #pragma unroll
                        for (int cof = 0; cof < 4; ++cof)
                            acc[0][pxf][cof] = __builtin_amdgcn_mfma_f32_16x16x32_bf16(
                                aF[cof], bF, acc[0][pxf][cof], 0, 0, 0);
                    } else if (cz == 1) {
                        #pragma unroll
                        for (int cof = 0; cof < 4; ++cof)
                            acc[1][pxf][cof] = __builtin_amdgcn_mfma_f32_16x16x32_bf16(
                                aF[cof], bF, acc[1][pxf][cof], 0, 0, 0);
                    } else if (cz == 2) {
                        #pragma unroll
                        for (int cof = 0; cof < 4; ++cof)
                            acc[2][pxf][cof] = __builtin_amdgcn_mfma_f32_16x16x32_bf16(
                                aF[cof], bF, acc[2][pxf][cof], 0, 0, 0);
                    } else {
                        #pragma unroll
                        for (int cof = 0; cof < 4; ++cof)
                            acc[3][pxf][cof] = __builtin_amdgcn_mfma_f32_16x16x32_bf16(
                                aF[cof], bF, acc[3][pxf][cof], 0, 0, 0);
                    }
                }
            }
            if (cz < 3) {
                __syncthreads();   // w2S readers done
                const char* ws2 = (const char*)w2ws + (size_t)(ch*4 + cz + 1)*37888;
                #pragma unroll
                for (int i2 = 0; i2 < 4; ++i2)
                    dma16(ws2 + t*16 + i2*8192, (char*)w2S + t*16 + i2*8192);
                if (t < 320) dma16(ws2 + t*16 + 32768, (char*)w2S + t*16 + 32768);
                __syncthreads();   // w2S ready
            }
        }
    }

    // ---- epilogue: BN2 + relu + scatter.  wave w = row w of stripe ----
    const size_t ybase = (size_t)bn*256*HW + (size_t)(row0 + pz*8 + w)*512 + col0;
    #pragma unroll
    for (int cz = 0; cz < 4; ++cz) {
        #pragma unroll
        for (int cof = 0; cof < 4; ++cof) {
            #pragma unroll
            for (int j = 0; j < 4; ++j) {
                const int co = cz*64 + cof*16 + g*4 + j;
                float s2 = s2S[co], t2 = t2S[co];
                #pragma unroll
                for (int pxf = 0; pxf < 2; ++pxf) {
                    y[ybase + (size_t)co*HW + pxf*16 + m] =
                        fmaxf(fmaf(acc[cz][pxf][cof][j], s2, t2), 0.f);
                }
            }
        }
    }
}

// ---------------------------------------------------------------------------
extern "C" void kernel_launch(void* const* d_in, const int* in_sizes, int n_in,
                              void* d_out, int out_size, void* d_ws, size_t ws_size,
                              hipStream_t stream) {
    const float* x       = (const float*)d_in[0];
    const int*   indices = (const int*)  d_in[2];
    const float* w1  = (const float*)d_in[3];
    const float* b1  = (const float*)d_in[4];
    const float* g1  = (const float*)d_in[5];
    const float* be1 = (const float*)d_in[6];
    const float* m1  = (const float*)d_in[7];
    const float* v1  = (const float*)d_in[8];
    const float* w2  = (const float*)d_in[9];
    const float* b2  = (const float*)d_in[10];
    const float* g2  = (const float*)d_in[11];
    const float* be2 = (const float*)d_in[12];
    const float* m2  = (const float*)d_in[13];
    const float* v2  = (const float*)d_in[14];
    const float* wd  = (const float*)d_in[21];
    const float* bd  = (const float*)d_in[22];
    const int* bstride = (const int*)d_in[24];
    const int* boff    = (const int*)d_in[25];
    float* y = (float*)d_out;
    char* ws = (char*)d_ws;

    const int nB = in_sizes[2] / 3;   // 256 blocks

    hipLaunchKernelGGL(kprep, dim3(2369), dim3(256), 0, stream,
                       w1, b1, g1, be1, m1, v1, w2, b2, g2, be2, m2, v2, ws);
    hipLaunchKernelGGL(k1_dense, dim3(2 * HW / 256), dim3(256), 0, stream,
                       x, wd, bd, y);
    hipLaunchKernelGGL(k2_fused, dim3(nB * 4), dim3(512), 118784, stream,
                       x, indices, ws, bstride, boff, y);
}

// Round 6
// 537.337 us; speedup vs baseline: 21.6296x; 2.0426x over previous
//
#include <hip/hip_runtime.h>

#define HW 262144   // 512*512
#define EPSF 1e-5f

typedef __attribute__((ext_vector_type(8))) short bf16x8;
typedef __attribute__((ext_vector_type(4))) float f32x4;

__device__ __forceinline__ unsigned short f2bf(float f) {
    unsigned u = __builtin_bit_cast(unsigned, f);
    return (unsigned short)((u + 0x7FFFu + ((u >> 16) & 1u)) >> 16);  // RNE
}

typedef __attribute__((address_space(3))) unsigned lds_u32_t;
typedef __attribute__((address_space(1))) const unsigned glb_u32_t;
__device__ __forceinline__ void dma16(const void* gsrc, void* ldst) {
    __builtin_amdgcn_global_load_lds((glb_u32_t*)gsrc, (lds_u32_t*)ldst, 16, 0, 0);
}

// ws layout (bytes):
//   w2ws @ 0        : [8ch][4cz][64co][296] ushort = 1,212,416
//   w1ws @ 1212416  : [256hc][72ci] ushort (BN1-folded) = 36,864
//   t1ws @ 1249280  : float[256]
//   s2ws @ 1250304  : float[256]
//   t2ws @ 1251328  : float[256]
//   wdws @ 1252352  : [256co][72ci] ushort = 36,864
//   mskw @ 1289216  : byte[512]  block bitmap from indices (NOT the bool input)
#define W2WS_OFF 0
#define W1WS_OFF 1212416
#define T1WS_OFF 1249280
#define S2WS_OFF 1250304
#define T2WS_OFF 1251328
#define WDWS_OFF 1252352
#define MSKWS_OFF 1289216

// ---------------------------------------------------------------------------
// kmask: build block-coverage bitmap [n][gh][gw] from indices (int32, safe).
// One block: zero, sync, set.
// ---------------------------------------------------------------------------
__global__ __launch_bounds__(512) void kmask(const int* __restrict__ indices,
                                             int nB, char* __restrict__ ws) {
    unsigned char* mb = (unsigned char*)(ws + MSKWS_OFF);
    const int t = threadIdx.x;
    if (t < 512) mb[t] = 0;
    __syncthreads();
    if (t < nB) {
        int bn = indices[t*3+0], gh = indices[t*3+1], gw = indices[t*3+2];
        if ((unsigned)bn < 2u && (unsigned)gh < 16u && (unsigned)gw < 16u)
            mb[bn*256 + gh*16 + gw] = 1;
    }
}

// ---------------------------------------------------------------------------
// kprep: one-shot weight transform into MFMA/DMA-friendly workspace.
// ---------------------------------------------------------------------------
__global__ __launch_bounds__(256) void kprep(
    const float* __restrict__ w1, const float* __restrict__ b1,
    const float* __restrict__ g1, const float* __restrict__ be1,
    const float* __restrict__ m1, const float* __restrict__ v1,
    const float* __restrict__ w2, const float* __restrict__ b2,
    const float* __restrict__ g2, const float* __restrict__ be2,
    const float* __restrict__ m2, const float* __restrict__ v2,
    const float* __restrict__ wd,
    char* __restrict__ ws)
{
    unsigned short* w2ws = (unsigned short*)(ws + W2WS_OFF);
    unsigned short* w1ws = (unsigned short*)(ws + W1WS_OFF);
    unsigned short* wdws = (unsigned short*)(ws + WDWS_OFF);
    float* t1ws = (float*)(ws + T1WS_OFF);
    float* s2ws = (float*)(ws + S2WS_OFF);
    float* t2ws = (float*)(ws + T2WS_OFF);

    const int bid = blockIdx.x, t = threadIdx.x;
    if (bid < 2304) {                      // w2: 589,824 elements
        int e  = bid*256 + t;
        int hc = e & 31;
        int r1 = e >> 5;
        int tap = r1 % 9;
        int r2 = r1 / 9;                   // < 2048
        int co = r2 & 63;
        int q  = r2 >> 6;                  // < 32
        int cz = q & 3, ch = q >> 2;
        float v = w2[(size_t)(cz*64+co)*2304 + (size_t)(ch*32+hc)*9 + tap];
        w2ws[((ch*4+cz)*64+co)*296 + tap*32 + hc] = f2bf(v);
    } else if (bid < 2368) {               // w1 folded: 16,384 elements
        int e = (bid-2304)*256 + t;
        int hc = e >> 6, ci = e & 63;
        float s1 = g1[hc] * rsqrtf(v1[hc] + EPSF);
        w1ws[hc*72 + ci] = f2bf(w1[hc*64+ci] * s1);
    } else if (bid < 2432) {               // wd: 16,384 elements
        int e = (bid-2368)*256 + t;
        int co = e >> 6, ci = e & 63;
        wdws[co*72 + ci] = f2bf(wd[co*64 + ci]);
    } else {
        if (t < 256) {
            float s1 = g1[t] * rsqrtf(v1[t] + EPSF);
            t1ws[t] = (b1[t]-m1[t])*s1 + be1[t];
            float s2 = g2[t] * rsqrtf(v2[t] + EPSF);
            s2ws[t] = s2;
            t2ws[t] = (b2[t]-m2[t])*s2 + be2[t];
        }
    }
}

// ---------------------------------------------------------------------------
// k1_mfma: dense 1x1 conv as implicit GEMM, bf16 MFMA.
// WG = (n, row, half): 256 px (half row) x 256 co. 256 thr = 4 waves.
// Stores in 32-px groups covered by a sparse block are SKIPPED (k2 writes
// them). Skip source: ws bitmap from indices (round-5 bug: bool input
// marshalling was not byte-per-element).
// ---------------------------------------------------------------------------
__global__ __launch_bounds__(256, 2) void k1_mfma(
    const float* __restrict__ x,
    const float* __restrict__ bd, const char* __restrict__ ws,
    const int* __restrict__ bstride, const int* __restrict__ boff,
    float* __restrict__ y)
{
    extern __shared__ char smem[];
    unsigned short* xT  = (unsigned short*)smem;            // [256][72] 36,864B
    unsigned short* wdS = (unsigned short*)(smem + 36864);  // [256][72] 36,864B
    float*          bdS = (float*)(smem + 73728);           // [256]      1,024B

    const int t = threadIdx.x, lane = t & 63, w = t >> 6;
    const int m = lane & 15, g = lane >> 4;
    const int bid = blockIdx.x;
    const int n   = bid >> 10;
    const int row = (bid >> 1) & 511;
    const int c0  = (bid & 1) * 256;

    // ---- DMA weight/bias tables ----
    #pragma unroll
    for (int i = 0; i < 9; ++i)
        dma16((const char*)ws + WDWS_OFF + (t + i*256)*16,
              (char*)wdS + (t + i*256)*16);
    if (t < 64) dma16((const char*)bd + t*16, (char*)bdS + t*16);

    // ---- stage xT: wave w covers ci = w+4*jc; lane covers px = lane*4..+3 ----
    const size_t xbase = (size_t)n*64*HW + (size_t)row*512 + c0;
    #pragma unroll 4
    for (int jc = 0; jc < 16; ++jc) {
        int ci = w + 4*jc;
        float4 xv = *(const float4*)&x[xbase + (size_t)ci*HW + lane*4];
        xT[(lane*4+0)*72 + ci] = f2bf(xv.x);
        xT[(lane*4+1)*72 + ci] = f2bf(xv.y);
        xT[(lane*4+2)*72 + ci] = f2bf(xv.z);
        xT[(lane*4+3)*72 + ci] = f2bf(xv.w);
    }

    // ---- mask word for store-skip (bitmap built from indices by kmask) ----
    const int stride = bstride[0], off = boff[0];
    const bool safe = (stride == 32) && (off == 0);
    unsigned long long mv = 0;
    if (safe) {
        const unsigned char* mb = (const unsigned char*)(ws + MSKWS_OFF);
        mv = *(const unsigned long long*)&mb[n*256 + (row>>5)*16 + (bid&1)*8];
    }

    __syncthreads();   // drains DMAs (vmcnt) + LDS writes

    // ---- B-frags (x) into registers: [kk][pxf] ----
    bf16x8 bF[2][4];
    #pragma unroll
    for (int pxf = 0; pxf < 4; ++pxf)
        #pragma unroll
        for (int kk = 0; kk < 2; ++kk)
            bF[kk][pxf] = *(const bf16x8*)&xT[(w*64 + pxf*16 + m)*72 + kk*32 + g*8];

    const size_t ybase = (size_t)(n*256)*HW + (size_t)row*512 + c0;
    #pragma unroll 1
    for (int cof = 0; cof < 16; ++cof) {
        bf16x8 a0 = *(const bf16x8*)&wdS[(cof*16+m)*72 +      g*8];
        bf16x8 a1 = *(const bf16x8*)&wdS[(cof*16+m)*72 + 32 + g*8];
        f32x4 ac[4];
        #pragma unroll
        for (int pxf = 0; pxf < 4; ++pxf) {
            ac[pxf] = (f32x4){0.f,0.f,0.f,0.f};
            ac[pxf] = __builtin_amdgcn_mfma_f32_16x16x32_bf16(a0, bF[0][pxf], ac[pxf], 0, 0, 0);
            ac[pxf] = __builtin_amdgcn_mfma_f32_16x16x32_bf16(a1, bF[1][pxf], ac[pxf], 0, 0, 0);
        }
        #pragma unroll
        for (int pxf = 0; pxf < 4; ++pxf) {
            const int pxg = w*4 + pxf;                 // 16-px group 0..15
            const bool skip = safe && (((mv >> ((pxg>>1)*8)) & 0xffull) != 0ull);
            if (!skip) {                               // wave-uniform branch
                #pragma unroll
                for (int j = 0; j < 4; ++j) {
                    const int co = cof*16 + g*4 + j;
                    y[ybase + (size_t)co*HW + pxg*16 + m] = ac[pxf][j] + bdS[co];
                }
            }
        }
    }
}

// ---------------------------------------------------------------------------
// k2_fused: unchanged (verified; ~360us).
// ---------------------------------------------------------------------------
__global__ __launch_bounds__(512, 2) void k2_fused(
    const float* __restrict__ x, const int* __restrict__ indices,
    const char* __restrict__ ws,
    const int* __restrict__ bstride, const int* __restrict__ boff,
    float* __restrict__ y)
{
    extern __shared__ char smem[];
    unsigned short* xT  = (unsigned short*)smem;            // [352][72]  50,688B
    unsigned short* w1s = (unsigned short*)(smem + 50688);  // [32][72]    4,608B
    unsigned short* hS  = (unsigned short*)(smem + 55296);  // [352][32]  22,528B
    unsigned short* w2S = (unsigned short*)(smem + 77824);  // [64][296]  37,888B
    float* t1S = (float*)(smem + 115712);
    float* s2S = (float*)(smem + 116736);
    float* t2S = (float*)(smem + 117760);                   // -> 118,784B

    const unsigned short* w2ws = (const unsigned short*)(ws + W2WS_OFF);
    const unsigned short* w1ws = (const unsigned short*)(ws + W1WS_OFF);

    const int t    = threadIdx.x;
    const int lane = t & 63;
    const int w    = t >> 6;
    const int m    = lane & 15;
    const int g    = lane >> 4;

    const int bid = blockIdx.x;
    const int blk = bid >> 2, pz = bid & 3;
    const int bn = indices[blk*3+0], gr = indices[blk*3+1], gc = indices[blk*3+2];
    const int stride = bstride[0], off = boff[0];
    const int row0 = gr*stride + off, col0 = gc*stride + off;

    if (t < 192) {
        const float* src = (t < 64) ? (const float*)(ws + T1WS_OFF)
                         : (t < 128) ? (const float*)(ws + S2WS_OFF)
                                     : (const float*)(ws + T2WS_OFF);
        float* dst = (t < 64) ? t1S : (t < 128) ? s2S : t2S;
        dma16(src + (lane)*4, dst + (lane)*4);
    }

    {
        const int half = lane >> 5, cc = lane & 31;
        for (int pb = w*80; pb < w*80 + 80; pb += 2) {
            int pi = pb + half;
            int r = pi >> 6, ci = pi & 63;
            int br = pz*8 + r - 1;
            if ((unsigned)br < 32u) {
                float xv = x[(size_t)bn*64*HW + (size_t)ci*HW
                             + (size_t)(row0+br)*512 + (col0+cc)];
                xT[(r*34 + cc + 1)*72 + ci] = f2bf(xv);
            }
        }
    }

    f32x4 acc[4][2][4];
    #pragma unroll
    for (int a = 0; a < 4; ++a)
        #pragma unroll
        for (int b = 0; b < 2; ++b)
            #pragma unroll
            for (int c = 0; c < 4; ++c) acc[a][b][c] = (f32x4){0.f,0.f,0.f,0.f};

    #pragma unroll 1
    for (int ch = 0; ch < 8; ++ch) {
        __syncthreads();

        if (t < 288) dma16((const char*)w1ws + ch*4608 + t*16, (char*)w1s + t*16);
        {
            const char* ws2 = (const char*)w2ws + (size_t)(ch*4 + 0)*37888;
            #pragma unroll
            for (int i = 0; i < 4; ++i)
                dma16(ws2 + t*16 + i*8192, (char*)w2S + t*16 + i*8192);
            if (t < 320) dma16(ws2 + t*16 + 32768, (char*)w2S + t*16 + 32768);
        }
        __syncthreads();

        f32x4 a1[3][2];
        #pragma unroll
        for (int i = 0; i < 3; ++i) { a1[i][0] = (f32x4){0,0,0,0}; a1[i][1] = (f32x4){0,0,0,0}; }
        #pragma unroll
        for (int i = 0; i < 3; ++i) {
            const int tile = w*3 + i;
            if (tile < 22) {
                #pragma unroll
                for (int kk = 0; kk < 2; ++kk) {
                    bf16x8 bF = *(const bf16x8*)&xT[(tile*16 + m)*72 + kk*32 + g*8];
                    #pragma unroll
                    for (int hct = 0; hct < 2; ++hct) {
                        bf16x8 aF = *(const bf16x8*)&w1s[(hct*16 + m)*72 + kk*32 + g*8];
                        a1[i][hct] = __builtin_amdgcn_mfma_f32_16x16x32_bf16(
                                         aF, bF, a1[i][hct], 0, 0, 0);
                    }
                }
            }
        }
        #pragma unroll
        for (int i = 0; i < 3; ++i) {
            const int tile = w*3 + i;
            if (tile < 22) {
                int p = tile*16 + m;
                int r = p / 34;
                int c = p - r*34;
                int br = pz*8 + r - 1;
                bool valid = (c >= 1) && (c <= 32) && ((unsigned)br < 32u);
                #pragma unroll
                for (int hct = 0; hct < 2; ++hct) {
                    unsigned short hv[4];
                    #pragma unroll
                    for (int j = 0; j < 4; ++j) {
                        float tv = t1S[ch*32 + hct*16 + g*4 + j];
                        float hf = fmaxf(a1[i][hct][j] + tv, 0.f);
                        hv[j] = valid ? f2bf(hf) : (unsigned short)0;
                    }
                    unsigned lo = (unsigned)hv[0] | ((unsigned)hv[1] << 16);
                    unsigned hi = (unsigned)hv[2] | ((unsigned)hv[3] << 16);
                    *(uint2*)&hS[p*32 + hct*16 + g*4] = make_uint2(lo, hi);
                }
            }
        }
        __syncthreads();

        #pragma unroll
        for (int cz = 0; cz < 4; ++cz) {
            #pragma unroll
            for (int tap = 0; tap < 9; ++tap) {
                const int dy = tap/3, dx = tap%3;
                bf16x8 aF[4];
                #pragma unroll
                for (int cof = 0; cof < 4; ++cof)
                    aF[cof] = *(const bf16x8*)&w2S[(cof*16 + m)*296 + tap*32 + g*8];
                #pragma unroll
                for (int pxf = 0; pxf < 2; ++pxf) {
                    int p = (w + dy)*34 + pxf*16 + m + dx;
                    bf16x8 bF = *(const bf16x8*)&hS[p*32 + g*8];
                    if (cz == 0) {
                        #pragma unroll
                        for (int cof = 0; cof < 4; ++cof)
                            acc[0][pxf][cof] = __builtin_amdgcn_mfma_f32_16x16x32_bf16(
                                aF[cof], bF, acc[0][pxf][cof], 0, 0, 0);
                    } else if (cz == 1) {
                        #pragma unroll
                        for (int cof = 0; cof < 4; ++cof)
                            acc[1][pxf][cof] = __builtin_amdgcn_mfma_f32_16x16x32_bf16(
                                aF[cof], bF, acc[1][pxf][cof], 0, 0, 0);
                    } else if (cz == 2) {
                        #pragma unroll
                        for (int cof = 0; cof < 4; ++cof)
                            acc[2][pxf][cof] = __builtin_amdgcn_mfma_f32_16x16x32_bf16(
                                aF[cof], bF, acc[2][pxf][cof], 0, 0, 0);
                    } else {
                        #pragma unroll
                        for (int cof = 0; cof < 4; ++cof)
                            acc[3][pxf][cof] = __builtin_amdgcn_mfma_f32_16x16x32_bf16(
                                aF[cof], bF, acc[3][pxf][cof], 0, 0, 0);
                    }
                }
            }
            if (cz < 3) {
                __syncthreads();
                const char* ws2 = (const char*)w2ws + (size_t)(ch*4 + cz + 1)*37888;
                #pragma unroll
                for (int i2 = 0; i2 < 4; ++i2)
                    dma16(ws2 + t*16 + i2*8192, (char*)w2S + t*16 + i2*8192);
                if (t < 320) dma16(ws2 + t*16 + 32768, (char*)w2S + t*16 + 32768);
                __syncthreads();
            }
        }
    }

    const size_t ybase = (size_t)bn*256*HW + (size_t)(row0 + pz*8 + w)*512 + col0;
    #pragma unroll
    for (int cz = 0; cz < 4; ++cz) {
        #pragma unroll
        for (int cof = 0; cof < 4; ++cof) {
            #pragma unroll
            for (int j = 0; j < 4; ++j) {
                const int co = cz*64 + cof*16 + g*4 + j;
                float s2 = s2S[co], t2 = t2S[co];
                #pragma unroll
                for (int pxf = 0; pxf < 2; ++pxf) {
                    y[ybase + (size_t)co*HW + pxf*16 + m] =
                        fmaxf(fmaf(acc[cz][pxf][cof][j], s2, t2), 0.f);
                }
            }
        }
    }
}

// ---------------------------------------------------------------------------
extern "C" void kernel_launch(void* const* d_in, const int* in_sizes, int n_in,
                              void* d_out, int out_size, void* d_ws, size_t ws_size,
                              hipStream_t stream) {
    const float* x       = (const float*)d_in[0];
    const int*   indices = (const int*)  d_in[2];
    const float* w1  = (const float*)d_in[3];
    const float* b1  = (const float*)d_in[4];
    const float* g1  = (const float*)d_in[5];
    const float* be1 = (const float*)d_in[6];
    const float* m1  = (const float*)d_in[7];
    const float* v1  = (const float*)d_in[8];
    const float* w2  = (const float*)d_in[9];
    const float* b2  = (const float*)d_in[10];
    const float* g2  = (const float*)d_in[11];
    const float* be2 = (const float*)d_in[12];
    const float* m2  = (const float*)d_in[13];
    const float* v2  = (const float*)d_in[14];
    const float* wd  = (const float*)d_in[21];
    const float* bd  = (const float*)d_in[22];
    const int* bstride = (const int*)d_in[24];
    const int* boff    = (const int*)d_in[25];
    float* y = (float*)d_out;
    char* ws = (char*)d_ws;

    const int nB = in_sizes[2] / 3;   // 256 blocks

    hipLaunchKernelGGL(kmask, dim3(1), dim3(512), 0, stream, indices, nB, ws);
    hipLaunchKernelGGL(kprep, dim3(2433), dim3(256), 0, stream,
                       w1, b1, g1, be1, m1, v1, w2, b2, g2, be2, m2, v2, wd, ws);
    hipLaunchKernelGGL(k1_mfma, dim3(2048), dim3(256), 74752, stream,
                       x, bd, ws, bstride, boff, y);
    hipLaunchKernelGGL(k2_fused, dim3(nB * 4), dim3(512), 118784, stream,
                       x, indices, ws, bstride, boff, y);
}

// Round 7
// 504.093 us; speedup vs baseline: 23.0561x; 1.0659x over previous
//
#include <hip/hip_runtime.h>

#define HW 262144   // 512*512
#define EPSF 1e-5f

typedef __attribute__((ext_vector_type(8))) short bf16x8;
typedef __attribute__((ext_vector_type(4))) float f32x4;

__device__ __forceinline__ unsigned short f2bf(float f) {
    unsigned u = __builtin_bit_cast(unsigned, f);
    return (unsigned short)((u + 0x7FFFu + ((u >> 16) & 1u)) >> 16);  // RNE
}

typedef __attribute__((address_space(3))) unsigned lds_u32_t;
typedef __attribute__((address_space(1))) const unsigned glb_u32_t;
__device__ __forceinline__ void dma16(const void* gsrc, void* ldst) {
    __builtin_amdgcn_global_load_lds((glb_u32_t*)gsrc, (lds_u32_t*)ldst, 16, 0, 0);
}

// ws layout (bytes):
//   w2ws @ 0        : [8ch][4cz][64co][296] ushort = 1,212,416
//   w1ws @ 1212416  : [256hc][72ci] ushort (BN1-folded) = 36,864
//   t1ws @ 1249280  : float[256]
//   s2ws @ 1250304  : float[256]
//   t2ws @ 1251328  : float[256]
//   wdws @ 1252352  : [256co][72ci] ushort = 36,864
//   mskw @ 1289216  : byte[512]  block bitmap from indices
#define W2WS_OFF 0
#define W1WS_OFF 1212416
#define T1WS_OFF 1249280
#define S2WS_OFF 1250304
#define T2WS_OFF 1251328
#define WDWS_OFF 1252352
#define MSKWS_OFF 1289216

// ---------------------------------------------------------------------------
// kmask: build block-coverage bitmap [n][gh][gw] from indices (int32, safe).
// ---------------------------------------------------------------------------
__global__ __launch_bounds__(512) void kmask(const int* __restrict__ indices,
                                             int nB, char* __restrict__ ws) {
    unsigned char* mb = (unsigned char*)(ws + MSKWS_OFF);
    const int t = threadIdx.x;
    if (t < 512) mb[t] = 0;
    __syncthreads();
    if (t < nB) {
        int bn = indices[t*3+0], gh = indices[t*3+1], gw = indices[t*3+2];
        if ((unsigned)bn < 2u && (unsigned)gh < 16u && (unsigned)gw < 16u)
            mb[bn*256 + gh*16 + gw] = 1;
    }
}

// ---------------------------------------------------------------------------
// kprep: one-shot weight transform into MFMA/DMA-friendly workspace.
// ---------------------------------------------------------------------------
__global__ __launch_bounds__(256) void kprep(
    const float* __restrict__ w1, const float* __restrict__ b1,
    const float* __restrict__ g1, const float* __restrict__ be1,
    const float* __restrict__ m1, const float* __restrict__ v1,
    const float* __restrict__ w2, const float* __restrict__ b2,
    const float* __restrict__ g2, const float* __restrict__ be2,
    const float* __restrict__ m2, const float* __restrict__ v2,
    const float* __restrict__ wd,
    char* __restrict__ ws)
{
    unsigned short* w2ws = (unsigned short*)(ws + W2WS_OFF);
    unsigned short* w1ws = (unsigned short*)(ws + W1WS_OFF);
    unsigned short* wdws = (unsigned short*)(ws + WDWS_OFF);
    float* t1ws = (float*)(ws + T1WS_OFF);
    float* s2ws = (float*)(ws + S2WS_OFF);
    float* t2ws = (float*)(ws + T2WS_OFF);

    const int bid = blockIdx.x, t = threadIdx.x;
    if (bid < 2304) {                      // w2: 589,824 elements
        int e  = bid*256 + t;
        int hc = e & 31;
        int r1 = e >> 5;
        int tap = r1 % 9;
        int r2 = r1 / 9;                   // < 2048
        int co = r2 & 63;
        int q  = r2 >> 6;                  // < 32
        int cz = q & 3, ch = q >> 2;
        float v = w2[(size_t)(cz*64+co)*2304 + (size_t)(ch*32+hc)*9 + tap];
        w2ws[((ch*4+cz)*64+co)*296 + tap*32 + hc] = f2bf(v);
    } else if (bid < 2368) {               // w1 folded: 16,384 elements
        int e = (bid-2304)*256 + t;
        int hc = e >> 6, ci = e & 63;
        float s1 = g1[hc] * rsqrtf(v1[hc] + EPSF);
        w1ws[hc*72 + ci] = f2bf(w1[hc*64+ci] * s1);
    } else if (bid < 2432) {               // wd: 16,384 elements
        int e = (bid-2368)*256 + t;
        int co = e >> 6, ci = e & 63;
        wdws[co*72 + ci] = f2bf(wd[co*64 + ci]);
    } else {
        if (t < 256) {
            float s1 = g1[t] * rsqrtf(v1[t] + EPSF);
            t1ws[t] = (b1[t]-m1[t])*s1 + be1[t];
            float s2 = g2[t] * rsqrtf(v2[t] + EPSF);
            s2ws[t] = s2;
            t2ws[t] = (b2[t]-m2[t])*s2 + be2[t];
        }
    }
}

// ---------------------------------------------------------------------------
// k1_mfma: dense 1x1 conv as implicit GEMM, bf16 MFMA, mask-skipped stores.
// (unchanged from round 6 — verified, ~60us)
// ---------------------------------------------------------------------------
__global__ __launch_bounds__(256, 2) void k1_mfma(
    const float* __restrict__ x,
    const float* __restrict__ bd, const char* __restrict__ ws,
    const int* __restrict__ bstride, const int* __restrict__ boff,
    float* __restrict__ y)
{
    extern __shared__ char smem[];
    unsigned short* xT  = (unsigned short*)smem;            // [256][72] 36,864B
    unsigned short* wdS = (unsigned short*)(smem + 36864);  // [256][72] 36,864B
    float*          bdS = (float*)(smem + 73728);           // [256]      1,024B

    const int t = threadIdx.x, lane = t & 63, w = t >> 6;
    const int m = lane & 15, g = lane >> 4;
    const int bid = blockIdx.x;
    const int n   = bid >> 10;
    const int row = (bid >> 1) & 511;
    const int c0  = (bid & 1) * 256;

    #pragma unroll
    for (int i = 0; i < 9; ++i)
        dma16((const char*)ws + WDWS_OFF + (t + i*256)*16,
              (char*)wdS + (t + i*256)*16);
    if (t < 64) dma16((const char*)bd + t*16, (char*)bdS + t*16);

    const size_t xbase = (size_t)n*64*HW + (size_t)row*512 + c0;
    #pragma unroll 4
    for (int jc = 0; jc < 16; ++jc) {
        int ci = w + 4*jc;
        float4 xv = *(const float4*)&x[xbase + (size_t)ci*HW + lane*4];
        xT[(lane*4+0)*72 + ci] = f2bf(xv.x);
        xT[(lane*4+1)*72 + ci] = f2bf(xv.y);
        xT[(lane*4+2)*72 + ci] = f2bf(xv.z);
        xT[(lane*4+3)*72 + ci] = f2bf(xv.w);
    }

    const int stride = bstride[0], off = boff[0];
    const bool safe = (stride == 32) && (off == 0);
    unsigned long long mv = 0;
    if (safe) {
        const unsigned char* mb = (const unsigned char*)(ws + MSKWS_OFF);
        mv = *(const unsigned long long*)&mb[n*256 + (row>>5)*16 + (bid&1)*8];
    }

    __syncthreads();

    bf16x8 bF[2][4];
    #pragma unroll
    for (int pxf = 0; pxf < 4; ++pxf)
        #pragma unroll
        for (int kk = 0; kk < 2; ++kk)
            bF[kk][pxf] = *(const bf16x8*)&xT[(w*64 + pxf*16 + m)*72 + kk*32 + g*8];

    const size_t ybase = (size_t)(n*256)*HW + (size_t)row*512 + c0;
    #pragma unroll 1
    for (int cof = 0; cof < 16; ++cof) {
        bf16x8 a0 = *(const bf16x8*)&wdS[(cof*16+m)*72 +      g*8];
        bf16x8 a1 = *(const bf16x8*)&wdS[(cof*16+m)*72 + 32 + g*8];
        f32x4 ac[4];
        #pragma unroll
        for (int pxf = 0; pxf < 4; ++pxf) {
            ac[pxf] = (f32x4){0.f,0.f,0.f,0.f};
            ac[pxf] = __builtin_amdgcn_mfma_f32_16x16x32_bf16(a0, bF[0][pxf], ac[pxf], 0, 0, 0);
            ac[pxf] = __builtin_amdgcn_mfma_f32_16x16x32_bf16(a1, bF[1][pxf], ac[pxf], 0, 0, 0);
        }
        #pragma unroll
        for (int pxf = 0; pxf < 4; ++pxf) {
            const int pxg = w*4 + pxf;
            const bool skip = safe && (((mv >> ((pxg>>1)*8)) & 0xffull) != 0ull);
            if (!skip) {
                #pragma unroll
                for (int j = 0; j < 4; ++j) {
                    const int co = cof*16 + g*4 + j;
                    y[ybase + (size_t)co*HW + pxg*16 + m] = ac[pxf][j] + bdS[co];
                }
            }
        }
    }
}

// ---------------------------------------------------------------------------
// k2_fused, round 7:
//  * hS padded to stride 40 ushort (80B = 20 words mod 32 -> 2-way, free)
//  * w2S double-buffered (w2A/w2B): DMA for cz+2 issued right after the
//    barrier freeing its buffer; every drain overlapped by a cz of MFMA
//  * s_setprio(1) around conv2 MFMA clusters
// LDS: xT 50,688 | w1s 4,608 | hS 28,160 | w2A 37,888 | w2B 37,888 |
//      tables 3,072  = 162,304 B (1 WG/CU)
// ---------------------------------------------------------------------------
#define DMA_W2(CH, CZ, BUF)                                                   \
    {                                                                         \
        const char* ws2_ = (const char*)w2ws + (size_t)((CH)*4 + (CZ))*37888; \
        _Pragma("unroll")                                                     \
        for (int i2_ = 0; i2_ < 4; ++i2_)                                     \
            dma16(ws2_ + t*16 + i2_*8192, (char*)(BUF) + t*16 + i2_*8192);    \
        if (t < 320) dma16(ws2_ + t*16 + 32768, (char*)(BUF) + t*16 + 32768); \
    }

#define CONV2_CZ(CZ, BUF)                                                     \
    {                                                                         \
        __builtin_amdgcn_s_setprio(1);                                        \
        _Pragma("unroll")                                                     \
        for (int tap = 0; tap < 9; ++tap) {                                   \
            const int dy = tap/3, dx = tap%3;                                 \
            bf16x8 aF[4];                                                     \
            _Pragma("unroll")                                                 \
            for (int cof = 0; cof < 4; ++cof)                                 \
                aF[cof] = *(const bf16x8*)&(BUF)[(cof*16 + m)*296 + tap*32 + g*8]; \
            _Pragma("unroll")                                                 \
            for (int pxf = 0; pxf < 2; ++pxf) {                               \
                int p_ = (w + dy)*34 + pxf*16 + m + dx;                       \
                bf16x8 bFr = *(const bf16x8*)&hS[p_*40 + g*8];                \
                _Pragma("unroll")                                             \
                for (int cof = 0; cof < 4; ++cof)                             \
                    acc[CZ][pxf][cof] = __builtin_amdgcn_mfma_f32_16x16x32_bf16( \
                        aF[cof], bFr, acc[CZ][pxf][cof], 0, 0, 0);            \
            }                                                                 \
        }                                                                     \
        __builtin_amdgcn_s_setprio(0);                                        \
    }

__global__ __launch_bounds__(512, 2) void k2_fused(
    const float* __restrict__ x, const int* __restrict__ indices,
    const char* __restrict__ ws,
    const int* __restrict__ bstride, const int* __restrict__ boff,
    float* __restrict__ y)
{
    extern __shared__ char smem[];
    unsigned short* xT  = (unsigned short*)smem;             // [352][72]  50,688B
    unsigned short* w1s = (unsigned short*)(smem + 50688);   // [32][72]    4,608B
    unsigned short* hS  = (unsigned short*)(smem + 55296);   // [352][40]  28,160B
    unsigned short* w2A = (unsigned short*)(smem + 83456);   // [64][296]  37,888B
    unsigned short* w2B = (unsigned short*)(smem + 121344);  // [64][296]  37,888B
    float* t1S = (float*)(smem + 159232);
    float* s2S = (float*)(smem + 160256);
    float* t2S = (float*)(smem + 161280);                    // -> 162,304B

    const unsigned short* w2ws = (const unsigned short*)(ws + W2WS_OFF);
    const unsigned short* w1ws = (const unsigned short*)(ws + W1WS_OFF);

    const int t    = threadIdx.x;
    const int lane = t & 63;
    const int w    = t >> 6;
    const int m    = lane & 15;
    const int g    = lane >> 4;

    const int bid = blockIdx.x;
    const int blk = bid >> 2, pz = bid & 3;
    const int bn = indices[blk*3+0], gr = indices[blk*3+1], gc = indices[blk*3+2];
    const int stride = bstride[0], off = boff[0];
    const int row0 = gr*stride + off, col0 = gc*stride + off;

    if (t < 192) {
        const float* src = (t < 64) ? (const float*)(ws + T1WS_OFF)
                         : (t < 128) ? (const float*)(ws + S2WS_OFF)
                                     : (const float*)(ws + T2WS_OFF);
        float* dst = (t < 64) ? t1S : (t < 128) ? s2S : t2S;
        dma16(src + (lane)*4, dst + (lane)*4);
    }

    {
        const int half = lane >> 5, cc = lane & 31;
        for (int pb = w*80; pb < w*80 + 80; pb += 2) {
            int pi = pb + half;
            int r = pi >> 6, ci = pi & 63;
            int br = pz*8 + r - 1;
            if ((unsigned)br < 32u) {
                float xv = x[(size_t)bn*64*HW + (size_t)ci*HW
                             + (size_t)(row0+br)*512 + (col0+cc)];
                xT[(r*34 + cc + 1)*72 + ci] = f2bf(xv);
            }
        }
    }

    f32x4 acc[4][2][4];
    #pragma unroll
    for (int a = 0; a < 4; ++a)
        #pragma unroll
        for (int b = 0; b < 2; ++b)
            #pragma unroll
            for (int c = 0; c < 4; ++c) acc[a][b][c] = (f32x4){0.f,0.f,0.f,0.f};

    #pragma unroll 1
    for (int ch = 0; ch < 8; ++ch) {
        __syncthreads();   // barA: all prev readers of w1s/hS/w2A/w2B done

        if (t < 288) dma16((const char*)w1ws + ch*4608 + t*16, (char*)w1s + t*16);
        DMA_W2(ch, 0, w2A);
        DMA_W2(ch, 1, w2B);
        __syncthreads();   // barB: drain (xT/tables also ready at ch=0)

        // ---- conv1 MFMA: wave w -> px-tiles w*3..w*3+2 (tile<22) ----
        f32x4 a1[3][2];
        #pragma unroll
        for (int i = 0; i < 3; ++i) { a1[i][0] = (f32x4){0,0,0,0}; a1[i][1] = (f32x4){0,0,0,0}; }
        #pragma unroll
        for (int i = 0; i < 3; ++i) {
            const int tile = w*3 + i;
            if (tile < 22) {
                #pragma unroll
                for (int kk = 0; kk < 2; ++kk) {
                    bf16x8 bF = *(const bf16x8*)&xT[(tile*16 + m)*72 + kk*32 + g*8];
                    #pragma unroll
                    for (int hct = 0; hct < 2; ++hct) {
                        bf16x8 aF = *(const bf16x8*)&w1s[(hct*16 + m)*72 + kk*32 + g*8];
                        a1[i][hct] = __builtin_amdgcn_mfma_f32_16x16x32_bf16(
                                         aF, bF, a1[i][hct], 0, 0, 0);
                    }
                }
            }
        }
        // ---- h write: BN1 bias + relu + border mask, bf16 ----
        #pragma unroll
        for (int i = 0; i < 3; ++i) {
            const int tile = w*3 + i;
            if (tile < 22) {
                int p = tile*16 + m;
                int r = p / 34;
                int c = p - r*34;
                int br = pz*8 + r - 1;
                bool valid = (c >= 1) && (c <= 32) && ((unsigned)br < 32u);
                #pragma unroll
                for (int hct = 0; hct < 2; ++hct) {
                    unsigned short hv[4];
                    #pragma unroll
                    for (int j = 0; j < 4; ++j) {
                        float tv = t1S[ch*32 + hct*16 + g*4 + j];
                        float hf = fmaxf(a1[i][hct][j] + tv, 0.f);
                        hv[j] = valid ? f2bf(hf) : (unsigned short)0;
                    }
                    unsigned lo = (unsigned)hv[0] | ((unsigned)hv[1] << 16);
                    unsigned hi = (unsigned)hv[2] | ((unsigned)hv[3] << 16);
                    *(uint2*)&hS[p*40 + hct*16 + g*4] = make_uint2(lo, hi);
                }
            }
        }
        __syncthreads();   // barC: hS ready

        CONV2_CZ(0, w2A);
        __syncthreads();   // barD: w2A readers (cz0) done
        DMA_W2(ch, 2, w2A);
        CONV2_CZ(1, w2B);  // buf resident since barB
        __syncthreads();   // barE: drains cz2 DMA; w2B readers (cz1) done
        DMA_W2(ch, 3, w2B);
        CONV2_CZ(2, w2A);
        __syncthreads();   // barF: drains cz3 DMA
        CONV2_CZ(3, w2B);
    }

    // ---- epilogue: BN2 + relu + scatter ----
    const size_t ybase = (size_t)bn*256*HW + (size_t)(row0 + pz*8 + w)*512 + col0;
    #pragma unroll
    for (int cz = 0; cz < 4; ++cz) {
        #pragma unroll
        for (int cof = 0; cof < 4; ++cof) {
            #pragma unroll
            for (int j = 0; j < 4; ++j) {
                const int co = cz*64 + cof*16 + g*4 + j;
                float s2 = s2S[co], t2 = t2S[co];
                #pragma unroll
                for (int pxf = 0; pxf < 2; ++pxf) {
                    y[ybase + (size_t)co*HW + pxf*16 + m] =
                        fmaxf(fmaf(acc[cz][pxf][cof][j], s2, t2), 0.f);
                }
            }
        }
    }
}

// ---------------------------------------------------------------------------
extern "C" void kernel_launch(void* const* d_in, const int* in_sizes, int n_in,
                              void* d_out, int out_size, void* d_ws, size_t ws_size,
                              hipStream_t stream) {
    const float* x       = (const float*)d_in[0];
    const int*   indices = (const int*)  d_in[2];
    const float* w1  = (const float*)d_in[3];
    const float* b1  = (const float*)d_in[4];
    const float* g1  = (const float*)d_in[5];
    const float* be1 = (const float*)d_in[6];
    const float* m1  = (const float*)d_in[7];
    const float* v1  = (const float*)d_in[8];
    const float* w2  = (const float*)d_in[9];
    const float* b2  = (const float*)d_in[10];
    const float* g2  = (const float*)d_in[11];
    const float* be2 = (const float*)d_in[12];
    const float* m2  = (const float*)d_in[13];
    const float* v2  = (const float*)d_in[14];
    const float* wd  = (const float*)d_in[21];
    const float* bd  = (const float*)d_in[22];
    const int* bstride = (const int*)d_in[24];
    const int* boff    = (const int*)d_in[25];
    float* y = (float*)d_out;
    char* ws = (char*)d_ws;

    const int nB = in_sizes[2] / 3;   // 256 blocks

    hipLaunchKernelGGL(kmask, dim3(1), dim3(512), 0, stream, indices, nB, ws);
    hipLaunchKernelGGL(kprep, dim3(2433), dim3(256), 0, stream,
                       w1, b1, g1, be1, m1, v1, w2, b2, g2, be2, m2, v2, wd, ws);
    hipLaunchKernelGGL(k1_mfma, dim3(2048), dim3(256), 74752, stream,
                       x, bd, ws, bstride, boff, y);
    hipLaunchKernelGGL(k2_fused, dim3(nB * 4), dim3(512), 162304, stream,
                       x, indices, ws, bstride, boff, y);
}

// Round 8
// 462.748 us; speedup vs baseline: 25.1161x; 1.0893x over previous
//
#include <hip/hip_runtime.h>

#define HW 262144   // 512*512
#define EPSF 1e-5f

typedef __attribute__((ext_vector_type(8))) short bf16x8;
typedef __attribute__((ext_vector_type(4))) float f32x4;

__device__ __forceinline__ unsigned short f2bf(float f) {
    unsigned u = __builtin_bit_cast(unsigned, f);
    return (unsigned short)((u + 0x7FFFu + ((u >> 16) & 1u)) >> 16);  // RNE
}

typedef __attribute__((address_space(3))) unsigned lds_u32_t;
typedef __attribute__((address_space(1))) const unsigned glb_u32_t;
__device__ __forceinline__ void dma16(const void* gsrc, void* ldst) {
    __builtin_amdgcn_global_load_lds((glb_u32_t*)gsrc, (lds_u32_t*)ldst, 16, 0, 0);
}

// ws layout (bytes):
//   w2ws @ 0        : [8ch][4cz][64co][296] ushort = 1,212,416
//   w1ws @ 1212416  : [256hc][72ci] ushort (BN1-folded) = 36,864
//   t1ws @ 1249280  : float[256]
//   s2ws @ 1250304  : float[256]
//   t2ws @ 1251328  : float[256]
//   wdws @ 1252352  : [256co][72ci] ushort = 36,864
//   mskw @ 1289216  : byte[512]
#define W2WS_OFF 0
#define W1WS_OFF 1212416
#define T1WS_OFF 1249280
#define S2WS_OFF 1250304
#define T2WS_OFF 1251328
#define WDWS_OFF 1252352
#define MSKWS_OFF 1289216

// ---------------------------------------------------------------------------
__global__ __launch_bounds__(512) void kmask(const int* __restrict__ indices,
                                             int nB, char* __restrict__ ws) {
    unsigned char* mb = (unsigned char*)(ws + MSKWS_OFF);
    const int t = threadIdx.x;
    if (t < 512) mb[t] = 0;
    __syncthreads();
    if (t < nB) {
        int bn = indices[t*3+0], gh = indices[t*3+1], gw = indices[t*3+2];
        if ((unsigned)bn < 2u && (unsigned)gh < 16u && (unsigned)gw < 16u)
            mb[bn*256 + gh*16 + gw] = 1;
    }
}

// ---------------------------------------------------------------------------
__global__ __launch_bounds__(256) void kprep(
    const float* __restrict__ w1, const float* __restrict__ b1,
    const float* __restrict__ g1, const float* __restrict__ be1,
    const float* __restrict__ m1, const float* __restrict__ v1,
    const float* __restrict__ w2, const float* __restrict__ b2,
    const float* __restrict__ g2, const float* __restrict__ be2,
    const float* __restrict__ m2, const float* __restrict__ v2,
    const float* __restrict__ wd,
    char* __restrict__ ws)
{
    unsigned short* w2ws = (unsigned short*)(ws + W2WS_OFF);
    unsigned short* w1ws = (unsigned short*)(ws + W1WS_OFF);
    unsigned short* wdws = (unsigned short*)(ws + WDWS_OFF);
    float* t1ws = (float*)(ws + T1WS_OFF);
    float* s2ws = (float*)(ws + S2WS_OFF);
    float* t2ws = (float*)(ws + T2WS_OFF);

    const int bid = blockIdx.x, t = threadIdx.x;
    if (bid < 2304) {                      // w2: 589,824 elements
        int e  = bid*256 + t;
        int hc = e & 31;
        int r1 = e >> 5;
        int tap = r1 % 9;
        int r2 = r1 / 9;                   // < 2048
        int co = r2 & 63;
        int q  = r2 >> 6;                  // < 32
        int cz = q & 3, ch = q >> 2;
        float v = w2[(size_t)(cz*64+co)*2304 + (size_t)(ch*32+hc)*9 + tap];
        w2ws[((ch*4+cz)*64+co)*296 + tap*32 + hc] = f2bf(v);
    } else if (bid < 2368) {               // w1 folded
        int e = (bid-2304)*256 + t;
        int hc = e >> 6, ci = e & 63;
        float s1 = g1[hc] * rsqrtf(v1[hc] + EPSF);
        w1ws[hc*72 + ci] = f2bf(w1[hc*64+ci] * s1);
    } else if (bid < 2432) {               // wd
        int e = (bid-2368)*256 + t;
        int co = e >> 6, ci = e & 63;
        wdws[co*72 + ci] = f2bf(wd[co*64 + ci]);
    } else {
        if (t < 256) {
            float s1 = g1[t] * rsqrtf(v1[t] + EPSF);
            t1ws[t] = (b1[t]-m1[t])*s1 + be1[t];
            float s2 = g2[t] * rsqrtf(v2[t] + EPSF);
            s2ws[t] = s2;
            t2ws[t] = (b2[t]-m2[t])*s2 + be2[t];
        }
    }
}

// ---------------------------------------------------------------------------
// k1_mfma: unchanged (verified, ~60us)
// ---------------------------------------------------------------------------
__global__ __launch_bounds__(256, 2) void k1_mfma(
    const float* __restrict__ x,
    const float* __restrict__ bd, const char* __restrict__ ws,
    const int* __restrict__ bstride, const int* __restrict__ boff,
    float* __restrict__ y)
{
    extern __shared__ char smem[];
    unsigned short* xT  = (unsigned short*)smem;            // [256][72]
    unsigned short* wdS = (unsigned short*)(smem + 36864);  // [256][72]
    float*          bdS = (float*)(smem + 73728);           // [256]

    const int t = threadIdx.x, lane = t & 63, w = t >> 6;
    const int m = lane & 15, g = lane >> 4;
    const int bid = blockIdx.x;
    const int n   = bid >> 10;
    const int row = (bid >> 1) & 511;
    const int c0  = (bid & 1) * 256;

    #pragma unroll
    for (int i = 0; i < 9; ++i)
        dma16((const char*)ws + WDWS_OFF + (t + i*256)*16,
              (char*)wdS + (t + i*256)*16);
    if (t < 64) dma16((const char*)bd + t*16, (char*)bdS + t*16);

    const size_t xbase = (size_t)n*64*HW + (size_t)row*512 + c0;
    #pragma unroll 4
    for (int jc = 0; jc < 16; ++jc) {
        int ci = w + 4*jc;
        float4 xv = *(const float4*)&x[xbase + (size_t)ci*HW + lane*4];
        xT[(lane*4+0)*72 + ci] = f2bf(xv.x);
        xT[(lane*4+1)*72 + ci] = f2bf(xv.y);
        xT[(lane*4+2)*72 + ci] = f2bf(xv.z);
        xT[(lane*4+3)*72 + ci] = f2bf(xv.w);
    }

    const int stride = bstride[0], off = boff[0];
    const bool safe = (stride == 32) && (off == 0);
    unsigned long long mv = 0;
    if (safe) {
        const unsigned char* mb = (const unsigned char*)(ws + MSKWS_OFF);
        mv = *(const unsigned long long*)&mb[n*256 + (row>>5)*16 + (bid&1)*8];
    }

    __syncthreads();

    bf16x8 bF[2][4];
    #pragma unroll
    for (int pxf = 0; pxf < 4; ++pxf)
        #pragma unroll
        for (int kk = 0; kk < 2; ++kk)
            bF[kk][pxf] = *(const bf16x8*)&xT[(w*64 + pxf*16 + m)*72 + kk*32 + g*8];

    const size_t ybase = (size_t)(n*256)*HW + (size_t)row*512 + c0;
    #pragma unroll 1
    for (int cof = 0; cof < 16; ++cof) {
        bf16x8 a0 = *(const bf16x8*)&wdS[(cof*16+m)*72 +      g*8];
        bf16x8 a1 = *(const bf16x8*)&wdS[(cof*16+m)*72 + 32 + g*8];
        f32x4 ac[4];
        #pragma unroll
        for (int pxf = 0; pxf < 4; ++pxf) {
            ac[pxf] = (f32x4){0.f,0.f,0.f,0.f};
            ac[pxf] = __builtin_amdgcn_mfma_f32_16x16x32_bf16(a0, bF[0][pxf], ac[pxf], 0, 0, 0);
            ac[pxf] = __builtin_amdgcn_mfma_f32_16x16x32_bf16(a1, bF[1][pxf], ac[pxf], 0, 0, 0);
        }
        #pragma unroll
        for (int pxf = 0; pxf < 4; ++pxf) {
            const int pxg = w*4 + pxf;
            const bool skip = safe && (((mv >> ((pxg>>1)*8)) & 0xffull) != 0ull);
            if (!skip) {
                #pragma unroll
                for (int j = 0; j < 4; ++j) {
                    const int co = cof*16 + g*4 + j;
                    y[ybase + (size_t)co*HW + pxg*16 + m] = ac[pxf][j] + bdS[co];
                }
            }
        }
    }
}

// ---------------------------------------------------------------------------
// k2_fused, round 8: LDS-traffic restructure.
// Per ch (32 hc): conv1 as before; conv2 runs TWO co-half passes (czh=0,1):
// single w2S buffer [128co][296].  Waves = 2 co-groups(64co) x 4 row-pairs
// (2 rows x 32 cols = 64 px): per tap 4 A-frags + 4 B-frags -> 16 MFMA
// (0.5 frags/MFMA vs 0.75 before; conv2 LDS reads/WG 13,824 -> 9,216).
// acc[2czh][4cof][4pxf] = 128 VGPR, static indexing.
// LDS: xT 50,688 | w1s 4,608 | hS 28,160 | w2S 75,776 | tables 3,072
//      = 162,304 B (1 WG/CU).
// ---------------------------------------------------------------------------
#define DMA_CZH(CH, CZH)                                                      \
    {                                                                         \
        const char* s_ = (const char*)w2ws                                    \
                         + (size_t)(CH)*151552 + (size_t)(CZH)*75776;         \
        _Pragma("unroll")                                                     \
        for (int i_ = 0; i_ < 9; ++i_)                                        \
            dma16(s_ + t*16 + i_*8192, (char*)w2S + t*16 + i_*8192);          \
        if (t < 128) dma16(s_ + 73728 + t*16, (char*)w2S + 73728 + t*16);     \
    }

#define CONV2_CZH(CZH)                                                        \
    {                                                                         \
        __builtin_amdgcn_s_setprio(1);                                        \
        _Pragma("unroll")                                                     \
        for (int tap = 0; tap < 9; ++tap) {                                   \
            const int dy = tap/3, dx = tap%3;                                 \
            bf16x8 aF[4];                                                     \
            _Pragma("unroll")                                                 \
            for (int cof = 0; cof < 4; ++cof)                                 \
                aF[cof] = *(const bf16x8*)&w2S[(cog*64 + cof*16 + m)*296      \
                                               + tap*32 + g*8];               \
            _Pragma("unroll")                                                 \
            for (int pxf = 0; pxf < 4; ++pxf) {                               \
                int p_ = (ph*2 + (pxf>>1) + dy)*34 + (pxf&1)*16 + m + dx;     \
                bf16x8 bFr = *(const bf16x8*)&hS[p_*40 + g*8];                \
                _Pragma("unroll")                                             \
                for (int cof = 0; cof < 4; ++cof)                             \
                    acc[CZH][cof][pxf] = __builtin_amdgcn_mfma_f32_16x16x32_bf16( \
                        aF[cof], bFr, acc[CZH][cof][pxf], 0, 0, 0);           \
            }                                                                 \
        }                                                                     \
        __builtin_amdgcn_s_setprio(0);                                        \
    }

__global__ __launch_bounds__(512, 2) void k2_fused(
    const float* __restrict__ x, const int* __restrict__ indices,
    const char* __restrict__ ws,
    const int* __restrict__ bstride, const int* __restrict__ boff,
    float* __restrict__ y)
{
    extern __shared__ char smem[];
    unsigned short* xT  = (unsigned short*)smem;             // [352][72]  50,688B
    unsigned short* w1s = (unsigned short*)(smem + 50688);   // [32][72]    4,608B
    unsigned short* hS  = (unsigned short*)(smem + 55296);   // [352][40]  28,160B
    unsigned short* w2S = (unsigned short*)(smem + 83456);   // [128][296] 75,776B
    float* t1S = (float*)(smem + 159232);
    float* s2S = (float*)(smem + 160256);
    float* t2S = (float*)(smem + 161280);                    // -> 162,304B

    const unsigned short* w2ws = (const unsigned short*)(ws + W2WS_OFF);
    const unsigned short* w1ws = (const unsigned short*)(ws + W1WS_OFF);

    const int t    = threadIdx.x;
    const int lane = t & 63;
    const int w    = t >> 6;
    const int m    = lane & 15;
    const int g    = lane >> 4;
    const int cog  = w >> 2;        // 0..1  co-group of 64 within the czh half
    const int ph   = w & 3;         // 0..3  row-pair (rows ph*2, ph*2+1)

    const int bid = blockIdx.x;
    const int blk = bid >> 2, pz = bid & 3;
    const int bn = indices[blk*3+0], gr = indices[blk*3+1], gc = indices[blk*3+2];
    const int stride = bstride[0], off = boff[0];
    const int row0 = gr*stride + off, col0 = gc*stride + off;

    if (t < 192) {
        const float* src = (t < 64) ? (const float*)(ws + T1WS_OFF)
                         : (t < 128) ? (const float*)(ws + S2WS_OFF)
                                     : (const float*)(ws + T2WS_OFF);
        float* dst = (t < 64) ? t1S : (t < 128) ? s2S : t2S;
        dma16(src + (lane)*4, dst + (lane)*4);
    }

    {   // stage xT (transpose to [px][ci], bf16), once
        const int half = lane >> 5, cc = lane & 31;
        for (int pb = w*80; pb < w*80 + 80; pb += 2) {
            int pi = pb + half;
            int r = pi >> 6, ci = pi & 63;
            int br = pz*8 + r - 1;
            if ((unsigned)br < 32u) {
                float xv = x[(size_t)bn*64*HW + (size_t)ci*HW
                             + (size_t)(row0+br)*512 + (col0+cc)];
                xT[(r*34 + cc + 1)*72 + ci] = f2bf(xv);
            }
        }
    }

    f32x4 acc[2][4][4];
    #pragma unroll
    for (int a = 0; a < 2; ++a)
        #pragma unroll
        for (int b = 0; b < 4; ++b)
            #pragma unroll
            for (int c = 0; c < 4; ++c) acc[a][b][c] = (f32x4){0.f,0.f,0.f,0.f};

    #pragma unroll 1
    for (int ch = 0; ch < 8; ++ch) {
        __syncthreads();   // barA: prev readers of w1s/hS/w2S done

        if (t < 288) dma16((const char*)w1ws + ch*4608 + t*16, (char*)w1s + t*16);
        DMA_CZH(ch, 0);
        __syncthreads();   // barB: drain (xT/tables also ready at ch=0)

        // ---- conv1 MFMA: wave w -> px-tiles w*3..w*3+2 (tile<22) ----
        f32x4 a1[3][2];
        #pragma unroll
        for (int i = 0; i < 3; ++i) { a1[i][0] = (f32x4){0,0,0,0}; a1[i][1] = (f32x4){0,0,0,0}; }
        #pragma unroll
        for (int i = 0; i < 3; ++i) {
            const int tile = w*3 + i;
            if (tile < 22) {
                #pragma unroll
                for (int kk = 0; kk < 2; ++kk) {
                    bf16x8 bF = *(const bf16x8*)&xT[(tile*16 + m)*72 + kk*32 + g*8];
                    #pragma unroll
                    for (int hct = 0; hct < 2; ++hct) {
                        bf16x8 aF = *(const bf16x8*)&w1s[(hct*16 + m)*72 + kk*32 + g*8];
                        a1[i][hct] = __builtin_amdgcn_mfma_f32_16x16x32_bf16(
                                         aF, bF, a1[i][hct], 0, 0, 0);
                    }
                }
            }
        }
        // ---- h write: BN1 bias + relu + border mask, bf16 ----
        #pragma unroll
        for (int i = 0; i < 3; ++i) {
            const int tile = w*3 + i;
            if (tile < 22) {
                int p = tile*16 + m;
                int r = p / 34;
                int c = p - r*34;
                int br = pz*8 + r - 1;
                bool valid = (c >= 1) && (c <= 32) && ((unsigned)br < 32u);
                #pragma unroll
                for (int hct = 0; hct < 2; ++hct) {
                    unsigned short hv[4];
                    #pragma unroll
                    for (int j = 0; j < 4; ++j) {
                        float tv = t1S[ch*32 + hct*16 + g*4 + j];
                        float hf = fmaxf(a1[i][hct][j] + tv, 0.f);
                        hv[j] = valid ? f2bf(hf) : (unsigned short)0;
                    }
                    unsigned lo = (unsigned)hv[0] | ((unsigned)hv[1] << 16);
                    unsigned hi = (unsigned)hv[2] | ((unsigned)hv[3] << 16);
                    *(uint2*)&hS[p*40 + hct*16 + g*4] = make_uint2(lo, hi);
                }
            }
        }
        __syncthreads();   // barC: hS ready (w2S czh0 ready since barB)

        CONV2_CZH(0);
        __syncthreads();   // barD: w2S (czh0) readers done
        DMA_CZH(ch, 1);
        __syncthreads();   // barE: drain
        CONV2_CZH(1);
    }

    // ---- epilogue: BN2 + relu + scatter ----
    const size_t yblk = (size_t)bn*256*HW;
    const int rbase = row0 + pz*8 + ph*2;
    #pragma unroll
    for (int czh = 0; czh < 2; ++czh) {
        #pragma unroll
        for (int cof = 0; cof < 4; ++cof) {
            #pragma unroll
            for (int j = 0; j < 4; ++j) {
                const int co = czh*128 + cog*64 + cof*16 + g*4 + j;
                float s2 = s2S[co], t2 = t2S[co];
                #pragma unroll
                for (int pxf = 0; pxf < 4; ++pxf) {
                    const int rr = rbase + (pxf>>1);
                    const int cc2 = col0 + (pxf&1)*16 + m;
                    y[yblk + (size_t)co*HW + (size_t)rr*512 + cc2] =
                        fmaxf(fmaf(acc[czh][cof][pxf][j], s2, t2), 0.f);
                }
            }
        }
    }
}

// ---------------------------------------------------------------------------
extern "C" void kernel_launch(void* const* d_in, const int* in_sizes, int n_in,
                              void* d_out, int out_size, void* d_ws, size_t ws_size,
                              hipStream_t stream) {
    const float* x       = (const float*)d_in[0];
    const int*   indices = (const int*)  d_in[2];
    const float* w1  = (const float*)d_in[3];
    const float* b1  = (const float*)d_in[4];
    const float* g1  = (const float*)d_in[5];
    const float* be1 = (const float*)d_in[6];
    const float* m1  = (const float*)d_in[7];
    const float* v1  = (const float*)d_in[8];
    const float* w2  = (const float*)d_in[9];
    const float* b2  = (const float*)d_in[10];
    const float* g2  = (const float*)d_in[11];
    const float* be2 = (const float*)d_in[12];
    const float* m2  = (const float*)d_in[13];
    const float* v2  = (const float*)d_in[14];
    const float* wd  = (const float*)d_in[21];
    const float* bd  = (const float*)d_in[22];
    const int* bstride = (const int*)d_in[24];
    const int* boff    = (const int*)d_in[25];
    float* y = (float*)d_out;
    char* ws = (char*)d_ws;

    const int nB = in_sizes[2] / 3;   // 256 blocks

    hipLaunchKernelGGL(kmask, dim3(1), dim3(512), 0, stream, indices, nB, ws);
    hipLaunchKernelGGL(kprep, dim3(2433), dim3(256), 0, stream,
                       w1, b1, g1, be1, m1, v1, w2, b2, g2, be2, m2, v2, wd, ws);
    hipLaunchKernelGGL(k1_mfma, dim3(2048), dim3(256), 74752, stream,
                       x, bd, ws, bstride, boff, y);
    hipLaunchKernelGGL(k2_fused, dim3(nB * 4), dim3(512), 162304, stream,
                       x, indices, ws, bstride, boff, y);
}